// Round 10
// baseline (95.258 us; speedup 1.0000x reference)
//
#include <hip/hip_runtime.h>
#include <hip/hip_bf16.h>
#include <hip/hip_cooperative_groups.h>

namespace cg = cooperative_groups;

#define NN   1024
#define MC   128                      // coarse grid size
#define HH   64
#define DYF  0.0009765625f            // 1/1024
#define SCL  2.8853900817779268f      // 2*log2(e): tanh(x) = 1 - 2/(2^(SCL*x)+1)
#define CJ   (127.0f / 1023.0f)       // fine index -> coarse position

typedef __attribute__((ext_vector_type(4)))  float f32x4;
typedef __attribute__((ext_vector_type(16))) float f32x16;
typedef __attribute__((ext_vector_type(8)))  short bf16x8s;

// tanh(x) = 1 - 2/(exp2(SCL*x)+1)  (exact identity, SCL = 2*log2 e)
__device__ __forceinline__ float tfast(float x) {
  float e = __builtin_amdgcn_exp2f(SCL * x);
  return 1.0f - 2.0f * __builtin_amdgcn_rcpf(e + 1.0f);
}

// coarse node y-value: linspace(DY, 1-DY, 128)
__device__ __forceinline__ float ynode(int m) {
  return DYF + (float)m * ((1.0f - 2.0f * DYF) / 127.0f);
}

__device__ __forceinline__ ushort bf16bits(float v) {
  __hip_bfloat16 hb = __float2bfloat16(v);
  return *reinterpret_cast<ushort*>(&hb);
}

// One cooperative kernel: 256 blocks x 64 threads (all co-resident).
// Phase 0: prep (EaC/EcC, W2f, b2c, ghat, Uhat=0, hom -> out)
// Phase 1: coarse 128x128 MFMA integral -> Uhat (atomicAdd)
// Phase 2: out[i] += lerp(Uhat)
__global__ __launch_bounds__(64) void fused_kernel(
    const float* __restrict__ f,   const float* __restrict__ ys,
    const float* __restrict__ W1,  const float* __restrict__ b1,
    const float* __restrict__ W2,  const float* __restrict__ b2,
    const float* __restrict__ W3,  const float* __restrict__ b3,
    const float* __restrict__ Hw1, const float* __restrict__ Hb1,
    const float* __restrict__ Hw2, const float* __restrict__ Hb2,
    float* __restrict__ EaC, float* __restrict__ EcC,
    ushort* __restrict__ W2f, float* __restrict__ b2c,
    float* __restrict__ ghat, float* __restrict__ Uhat,
    float* __restrict__ out)
{
  cg::grid_group grid = cg::this_grid();
  const int blk = blockIdx.x, t = threadIdx.x;
  const int gid = blk * 64 + t;

  // ======================= phase 0: prep ====================================
  if (blk < 128) {
    // EaC/EcC: one element each (gid = row*64 + m)
    int row = gid >> 6, m = gid & 63;
    float y = ynode(row);
    EaC[gid] = __builtin_amdgcn_exp2f(SCL * y * W1[m]);
    EcC[gid] = __builtin_amdgcn_exp2f(SCL * fmaf(y, W1[HH + m], b1[m]));
  } else if (blk < 192) {
    // W2f bf16(-2*SCL*W2), B-fragment order
    int w = gid - 8192;     // 0..4095
    int e = w & 7, c2 = (w >> 3) & 31, h = (w >> 8) & 1, ks = (w >> 9) & 3, tl = w >> 11;
    int k = ks * 16 + h * 8 + e;
    W2f[w] = bf16bits(-2.0f * SCL * W2[k * HH + tl * 32 + c2]);
  } else if (blk == 192) {
    // b2c[l] = SCL*(b2[l] + sum_m W2[m][l])
    float cs = 0.0f;
    #pragma unroll
    for (int m = 0; m < HH; ++m) cs += W2[m * HH + t];
    b2c[t] = SCL * (b2[t] + cs);
  } else if (blk < 195) {
    // ghat[node] = sum_j w(j,node)*f[j]*DY
    int node = gid - 12352;   // 0..127
    int jlo = (int)fmaxf(0.0f,    floorf((node - 1) * (1.0f / CJ)) - 1.0f);
    int jhi = (int)fminf(1023.0f, ceilf((node + 1) * (1.0f / CJ)) + 1.0f);
    float acc = 0.0f;
    for (int j = jlo; j <= jhi; ++j) {
      float w = 1.0f - fabsf((float)j * CJ - (float)node);
      if (w > 0.0f) acc = fmaf(w, f[j], acc);
    }
    ghat[node] = acc * DYF;
  } else if (blk == 195) {
    Uhat[t] = 0.0f; Uhat[64 + t] = 0.0f;
    if (t < 8) Uhat[128 + t] = 0.0f;
  } else if (blk < 228) {
    // hom: 2 threads per i; wave-reduce G = sum f and sw3 = sum W3 first
    const float4* f4 = (const float4*)f;
    float g = 0.0f;
    #pragma unroll
    for (int q = 0; q < 4; ++q) {
      float4 v = f4[t * 4 + q];
      g += v.x + v.y + v.z + v.w;
    }
    g += __shfl_xor(g, 1);  g += __shfl_xor(g, 2);  g += __shfl_xor(g, 4);
    g += __shfl_xor(g, 8);  g += __shfl_xor(g, 16); g += __shfl_xor(g, 32);
    float sw3 = W3[t];
    sw3 += __shfl_xor(sw3, 1);  sw3 += __shfl_xor(sw3, 2);  sw3 += __shfl_xor(sw3, 4);
    sw3 += __shfl_xor(sw3, 8);  sw3 += __shfl_xor(sw3, 16); sw3 += __shfl_xor(sw3, 32);
    int tid2 = (blk - 196) * 64 + t;
    int i = tid2 >> 1, p = tid2 & 1;
    float y = ys[i];
    float hom = 0.0f;
    #pragma unroll
    for (int q = 0; q < 32; ++q) {
      int l = p * 32 + q;
      hom += Hw2[l] * tfast(fmaf(y, Hw1[l], Hb1[l]));   // tfast(x) == tanh(x)
    }
    hom += __shfl_xor(hom, 1);   // combine the two halves for this i
    if (p == 0) out[i] = hom + Hb2[0] + (b3[0] + sw3) * g * DYF;
  }

  __threadfence();
  grid.sync();

  // ======================= phase 1: main (all 256 blocks = 256 waves) =======
  {
    const int l    = t;
    const int W    = blk;
    const int ib   = (W & 3) * 32;           // coarse i-tile base (4 tiles)
    const int j0   = (W >> 2) * 2;           // coarse j base (64 slices of 2)
    const int half = l >> 5;
    const int c    = l & 31;
    const int b4   = half * 2;

    const bf16x8s* w2v = (const bf16x8s*)W2f;
    bf16x8s B0[4], B1[4];
    #pragma unroll
    for (int ks = 0; ks < 4; ++ks) {
      B0[ks] = w2v[((0 * 4 + ks) * 2 + half) * 32 + c];
      B1[ks] = w2v[((1 * 4 + ks) * 2 + half) * 32 + c];
    }

    const f32x4* arow = (const f32x4*)(EaC + (size_t)(ib + c) * HH);
    f32x4 A[8];
    #pragma unroll
    for (int ks = 0; ks < 4; ++ks) {
      A[ks * 2]     = arow[ks * 4 + b4];
      A[ks * 2 + 1] = arow[ks * 4 + b4 + 1];
    }

    const float cst0 = b2c[c],  cst1 = b2c[32 + c];
    const float w3m0 = -2.0f * W3[c], w3m1 = -2.0f * W3[32 + c];  // DY in ghat

    f32x16 u{};

#define LOADC(CR, jj) do {                                                  \
    const f32x4* crow = (const f32x4*)(EcC + (size_t)(jj) * HH);            \
    CR[0] = crow[b4];      CR[1] = crow[b4 + 1];                            \
    CR[2] = crow[4 + b4];  CR[3] = crow[4 + b4 + 1];                        \
    CR[4] = crow[8 + b4];  CR[5] = crow[8 + b4 + 1];                        \
    CR[6] = crow[12 + b4]; CR[7] = crow[12 + b4 + 1];                       \
  } while (0)

#define COMPUTE(CR, jj) do {                                                \
    float fjv = ghat[jj];                                                   \
    float wg0 = w3m0 * fjv, wg1 = w3m1 * fjv;                               \
    f32x16 acc0, acc1;                                                      \
    _Pragma("unroll")                                                       \
    for (int r = 0; r < 16; ++r) { acc0[r] = cst0; acc1[r] = cst1; }        \
    _Pragma("unroll")                                                       \
    for (int ks = 0; ks < 4; ++ks) {                                        \
      float tt[8];                                                          \
      f32x4 z0 = A[ks * 2]     * CR[ks * 2];                                \
      f32x4 z1 = A[ks * 2 + 1] * CR[ks * 2 + 1];                            \
      _Pragma("unroll")                                                     \
      for (int e = 0; e < 4; ++e) {                                         \
        tt[e]     = __builtin_amdgcn_rcpf(z0[e] + 1.0f);                    \
        tt[4 + e] = __builtin_amdgcn_rcpf(z1[e] + 1.0f);                    \
      }                                                                     \
      union { bf16x8s s; __hip_bfloat162 h[4]; } fr;                        \
      fr.h[0] = __float22bfloat162_rn(make_float2(tt[0], tt[1]));           \
      fr.h[1] = __float22bfloat162_rn(make_float2(tt[2], tt[3]));           \
      fr.h[2] = __float22bfloat162_rn(make_float2(tt[4], tt[5]));           \
      fr.h[3] = __float22bfloat162_rn(make_float2(tt[6], tt[7]));           \
      acc0 = __builtin_amdgcn_mfma_f32_32x32x16_bf16(fr.s, B0[ks], acc0, 0, 0, 0); \
      acc1 = __builtin_amdgcn_mfma_f32_32x32x16_bf16(fr.s, B1[ks], acc1, 0, 0, 0); \
    }                                                                       \
    _Pragma("unroll")                                                       \
    for (int r = 0; r < 16; ++r) {                                          \
      float e0 = __builtin_amdgcn_exp2f(acc0[r]);                           \
      float r0 = __builtin_amdgcn_rcpf(e0 + 1.0f);                          \
      float e1 = __builtin_amdgcn_exp2f(acc1[r]);                           \
      float r1 = __builtin_amdgcn_rcpf(e1 + 1.0f);                          \
      u[r] = fmaf(r0, wg0, fmaf(r1, wg1, u[r]));                            \
    }                                                                       \
  } while (0)

    f32x4 CA[8], CB[8];
    LOADC(CA, j0);
    LOADC(CB, j0 + 1);
    COMPUTE(CA, j0);
    COMPUTE(CB, j0 + 1);

    #pragma unroll
    for (int r = 0; r < 16; ++r) {
      float v = u[r];
      v += __shfl_xor(v, 1);
      v += __shfl_xor(v, 2);
      v += __shfl_xor(v, 4);
      v += __shfl_xor(v, 8);
      v += __shfl_xor(v, 16);
      if (c == 0) {
        int row = (r & 3) + 8 * (r >> 2) + 4 * half;
        atomicAdd(&Uhat[ib + row], v);
      }
    }
#undef LOADC
#undef COMPUTE
  }

  __threadfence();
  grid.sync();

  // ======================= phase 2: interpolate =============================
  if (blk < 16) {
    int i = gid;
    float pos = (float)i * CJ;
    int m = (int)pos;
    m = m > 126 ? 126 : m;
    float tt = pos - (float)m;
    out[i] += fmaf(tt, Uhat[m + 1] - Uhat[m], Uhat[m]);
  }
}

extern "C" void kernel_launch(void* const* d_in, const int* in_sizes, int n_in,
                              void* d_out, int out_size, void* d_ws, size_t ws_size,
                              hipStream_t stream) {
  const float* f   = (const float*)d_in[0];
  const float* ys  = (const float*)d_in[1];
  const float* W1  = (const float*)d_in[2];
  const float* b1  = (const float*)d_in[3];
  const float* W2  = (const float*)d_in[4];
  const float* b2  = (const float*)d_in[5];
  const float* W3  = (const float*)d_in[6];
  const float* b3  = (const float*)d_in[7];
  const float* Hw1 = (const float*)d_in[8];
  const float* Hb1 = (const float*)d_in[9];
  const float* Hw2 = (const float*)d_in[10];
  const float* Hb2 = (const float*)d_in[11];
  float* out = (float*)d_out;

  float*  EaC  = (float*)d_ws;                   // 128*64 f32
  float*  EcC  = EaC + MC * HH;                  // 128*64 f32
  ushort* W2f  = (ushort*)(EcC + MC * HH);       // 4096 bf16
  float*  b2c  = (float*)(W2f + 4096);           // 64 f32
  float*  ghat = b2c + HH;                       // 128 f32 (+pad)
  float*  Uhat = ghat + 136;                     // 136 f32

  void* args[] = { (void*)&f, (void*)&ys, (void*)&W1, (void*)&b1,
                   (void*)&W2, (void*)&b2, (void*)&W3, (void*)&b3,
                   (void*)&Hw1, (void*)&Hb1, (void*)&Hw2, (void*)&Hb2,
                   (void*)&EaC, (void*)&EcC, (void*)&W2f, (void*)&b2c,
                   (void*)&ghat, (void*)&Uhat, (void*)&out };
  hipLaunchCooperativeKernel((void*)fused_kernel, dim3(256), dim3(64),
                             args, 0, stream);
}

// Round 11
// 30.158 us; speedup vs baseline: 3.1586x; 3.1586x over previous
//
#include <hip/hip_runtime.h>
#include <hip/hip_bf16.h>

#define HH   64
#define DYF  0.0009765625f            // 1/1024
#define SCL  2.8853900817779268f      // 2*log2(e): tanh(x) = 1 - 2/(2^(SCL*x)+1)
#define CJ   (127.0f / 1023.0f)       // fine index -> coarse position
#define INV  (1023.0f / 127.0f)       // coarse -> fine

typedef __attribute__((ext_vector_type(4)))  float f32x4;
typedef __attribute__((ext_vector_type(16))) float f32x16;
typedef __attribute__((ext_vector_type(8)))  short bf16x8s;

// coarse node y-value: linspace(DY, 1-DY, 128)
__device__ __forceinline__ float ynode(int m) {
  return DYF + (float)m * ((1.0f - 2.0f * DYF) / 127.0f);
}

__device__ __forceinline__ ushort bf16bits(float v) {
  __hip_bfloat16 hb = __float2bfloat16(v);
  return *reinterpret_cast<ushort*>(&hb);
}

// 512 blocks x 64 threads, zero inter-block sync. Block = (itile, coarse j):
//  - builds all fragments locally (W2 gather, exp2 prep, ghat gather)
//  - b2 + colsum constant via MFMA-with-ones (consistent bf16 weights)
//  - computes 32 coarse-row contributions for its j, scatters them into
//    out[] through the transposed lerp weights (atomicAdd)
//  - also adds the exact hom term for its 2 owned fine i's
// out[] is zeroed by a memset node; everything accumulates atomically.
__global__ __launch_bounds__(64) void fused_kernel(
    const float* __restrict__ f,   const float* __restrict__ ys,
    const float* __restrict__ W1,  const float* __restrict__ b1,
    const float* __restrict__ W2,  const float* __restrict__ b2,
    const float* __restrict__ W3,  const float* __restrict__ b3,
    const float* __restrict__ Hw1, const float* __restrict__ Hb1,
    const float* __restrict__ Hw2, const float* __restrict__ Hb2,
    float* __restrict__ out)
{
  const int t     = threadIdx.x;
  const int blk   = blockIdx.x;
  const int half  = t >> 5;
  const int c     = t & 31;
  const int itile = blk & 3;          // coarse i-tile (32 rows each)
  const int jc    = blk >> 2;         // coarse j, 0..127

  // ---- B fragments from W2 (bf16(-2*SCL*W2), B-frag order) -----------------
  bf16x8s B0[4], B1[4];
  #pragma unroll
  for (int ks = 0; ks < 4; ++ks) {
    #pragma unroll
    for (int e = 0; e < 8; ++e) {
      int k = ks * 16 + half * 8 + e;
      B0[ks][e] = (short)bf16bits(-2.0f * SCL * W2[k * HH + c]);
      B1[ks][e] = (short)bf16bits(-2.0f * SCL * W2[k * HH + 32 + c]);
    }
  }

  // ---- colsum via ones-MFMA: cs[col] = sum_k W2f[k][col] -------------------
  bf16x8s ones;
  #pragma unroll
  for (int e = 0; e < 8; ++e) ones[e] = (short)0x3F80;   // bf16 1.0
  f32x16 cs0{}, cs1{};
  #pragma unroll
  for (int ks = 0; ks < 4; ++ks) {
    cs0 = __builtin_amdgcn_mfma_f32_32x32x16_bf16(ones, B0[ks], cs0, 0, 0, 0);
    cs1 = __builtin_amdgcn_mfma_f32_32x32x16_bf16(ones, B1[ks], cs1, 0, 0, 0);
  }
  const float cst0 = fmaf(-0.5f, cs0[0], SCL * b2[c]);
  const float cst1 = fmaf(-0.5f, cs1[0], SCL * b2[32 + c]);

  // ---- A fragments: exp2(SCL * y_row * W1[0][m]), row = itile*32 + c -------
  const float yr = ynode(itile * 32 + c);
  f32x4 Af[8], Cf[8];
  const float yj = ynode(jc);
  #pragma unroll
  for (int ks = 0; ks < 4; ++ks) {
    #pragma unroll
    for (int q = 0; q < 2; ++q) {
      #pragma unroll
      for (int e = 0; e < 4; ++e) {
        int m = ks * 16 + half * 8 + q * 4 + e;
        Af[ks * 2 + q][e] = __builtin_amdgcn_exp2f(SCL * yr * W1[m]);
        Cf[ks * 2 + q][e] = __builtin_amdgcn_exp2f(SCL * fmaf(yj, W1[HH + m], b1[m]));
      }
    }
  }

  // ---- ghat(jc) = sum_j w(j,jc) * f[j] * DY (all lanes redundant) ----------
  float g = 0.0f;
  {
    int jlo = (int)ceilf((float)(jc - 1) * INV);
    if (jlo < 0) jlo = 0;
    for (int s = 0; s < 18; ++s) {
      int j = jlo + s;
      if (j > 1023) break;
      float w = 1.0f - fabsf((float)j * CJ - (float)jc);
      if (w > 0.0f) g = fmaf(w, f[j], g);
    }
  }
  const float fjv = g * DYF;
  const float wg0 = -2.0f * W3[c] * fjv;
  const float wg1 = -2.0f * W3[32 + c] * fjv;

  // ---- hom for this block's 2 fine i's (exact) -----------------------------
  {
    const float4* f4 = (const float4*)f;
    float G = 0.0f;
    #pragma unroll
    for (int q = 0; q < 4; ++q) {
      float4 v = f4[t * 4 + q];
      G += v.x + v.y + v.z + v.w;
    }
    G += __shfl_xor(G, 1);  G += __shfl_xor(G, 2);  G += __shfl_xor(G, 4);
    G += __shfl_xor(G, 8);  G += __shfl_xor(G, 16); G += __shfl_xor(G, 32);
    float sw3 = W3[t];
    sw3 += __shfl_xor(sw3, 1);  sw3 += __shfl_xor(sw3, 2);  sw3 += __shfl_xor(sw3, 4);
    sw3 += __shfl_xor(sw3, 8);  sw3 += __shfl_xor(sw3, 16); sw3 += __shfl_xor(sw3, 32);

    int i2 = blk * 2 + half;            // 0..1023, each owned once
    float yi = ys[i2];
    float hom = 0.0f;
    #pragma unroll
    for (int q = 0; q < 2; ++q) {
      int l = c * 2 + q;
      float e = __builtin_amdgcn_exp2f(SCL * fmaf(yi, Hw1[l], Hb1[l]));
      float th = 1.0f - 2.0f * __builtin_amdgcn_rcpf(e + 1.0f);   // tanh
      hom = fmaf(Hw2[l], th, hom);
    }
    hom += __shfl_xor(hom, 1);  hom += __shfl_xor(hom, 2);
    hom += __shfl_xor(hom, 4);  hom += __shfl_xor(hom, 8);
    hom += __shfl_xor(hom, 16);
    if (c == 0)
      atomicAdd(&out[i2], hom + Hb2[0] + (b3[0] + sw3) * G * DYF);
  }

  // ---- main: one coarse j, 32 coarse rows ----------------------------------
  f32x16 acc0, acc1;
  #pragma unroll
  for (int r = 0; r < 16; ++r) { acc0[r] = cst0; acc1[r] = cst1; }

  #pragma unroll
  for (int ks = 0; ks < 4; ++ks) {
    float tt[8];
    f32x4 z0 = Af[ks * 2]     * Cf[ks * 2];       // exp2(a'+c')
    f32x4 z1 = Af[ks * 2 + 1] * Cf[ks * 2 + 1];
    #pragma unroll
    for (int e = 0; e < 4; ++e) {
      tt[e]     = __builtin_amdgcn_rcpf(z0[e] + 1.0f);
      tt[4 + e] = __builtin_amdgcn_rcpf(z1[e] + 1.0f);
    }
    union { bf16x8s s; __hip_bfloat162 h[4]; } fr;
    fr.h[0] = __float22bfloat162_rn(make_float2(tt[0], tt[1]));
    fr.h[1] = __float22bfloat162_rn(make_float2(tt[2], tt[3]));
    fr.h[2] = __float22bfloat162_rn(make_float2(tt[4], tt[5]));
    fr.h[3] = __float22bfloat162_rn(make_float2(tt[6], tt[7]));
    acc0 = __builtin_amdgcn_mfma_f32_32x32x16_bf16(fr.s, B0[ks], acc0, 0, 0, 0);
    acc1 = __builtin_amdgcn_mfma_f32_32x32x16_bf16(fr.s, B1[ks], acc1, 0, 0, 0);
  }

  // ---- epilogue + reduce + transposed-lerp scatter -------------------------
  #pragma unroll
  for (int r = 0; r < 16; ++r) {
    float e0 = __builtin_amdgcn_exp2f(acc0[r]);
    float r0 = __builtin_amdgcn_rcpf(e0 + 1.0f);
    float e1 = __builtin_amdgcn_exp2f(acc1[r]);
    float r1 = __builtin_amdgcn_rcpf(e1 + 1.0f);
    float v = fmaf(r0, wg0, r1 * wg1);
    // reduce across the 32 lanes of this half (butterfly -> all lanes have v)
    v += __shfl_xor(v, 1);
    v += __shfl_xor(v, 2);
    v += __shfl_xor(v, 4);
    v += __shfl_xor(v, 8);
    v += __shfl_xor(v, 16);
    // coarse row I; scatter to the ~17 fine i's under its lerp hat
    int I = itile * 32 + (r & 3) + 8 * (r >> 2) + 4 * half;
    int ilo = (int)ceilf((float)(I - 1) * INV);
    if (ilo < 0) ilo = 0;
    int i = ilo + c;                    // c = 0..31; only ~17 lanes get w>0
    float w = 1.0f - fabsf((float)i * CJ - (float)I);
    if (w > 0.0f && i <= 1023)
      atomicAdd(&out[i], w * v);
  }
}

extern "C" void kernel_launch(void* const* d_in, const int* in_sizes, int n_in,
                              void* d_out, int out_size, void* d_ws, size_t ws_size,
                              hipStream_t stream) {
  const float* f   = (const float*)d_in[0];
  const float* ys  = (const float*)d_in[1];
  const float* W1  = (const float*)d_in[2];
  const float* b1  = (const float*)d_in[3];
  const float* W2  = (const float*)d_in[4];
  const float* b2  = (const float*)d_in[5];
  const float* W3  = (const float*)d_in[6];
  const float* b3  = (const float*)d_in[7];
  const float* Hw1 = (const float*)d_in[8];
  const float* Hb1 = (const float*)d_in[9];
  const float* Hw2 = (const float*)d_in[10];
  const float* Hb2 = (const float*)d_in[11];
  float* out = (float*)d_out;

  hipMemsetAsync(out, 0, 1024 * sizeof(float), stream);
  fused_kernel<<<512, 64, 0, stream>>>(f, ys, W1, b1, W2, b2, W3, b3,
                                       Hw1, Hb1, Hw2, Hb2, out);
}

// Round 12
// 16.758 us; speedup vs baseline: 5.6845x; 1.7997x over previous
//
#include <hip/hip_runtime.h>
#include <hip/hip_bf16.h>

#define HH   64
#define DYF  0.0009765625f            // 1/1024
#define SCL  2.8853900817779268f      // 2*log2(e): tanh(x) = 1 - 2/(2^(SCL*x)+1)
#define CJ   (127.0f / 1023.0f)       // fine index -> coarse position
#define INV  (1023.0f / 127.0f)       // coarse -> fine

typedef __attribute__((ext_vector_type(4)))  float f32x4;
typedef __attribute__((ext_vector_type(16))) float f32x16;
typedef __attribute__((ext_vector_type(8)))  short bf16x8s;

// coarse node y-value: linspace(DY, 1-DY, 128)
__device__ __forceinline__ float ynode(int m) {
  return DYF + (float)m * ((1.0f - 2.0f * DYF) / 127.0f);
}

__device__ __forceinline__ ushort bf16bits(float v) {
  __hip_bfloat16 hb = __float2bfloat16(v);
  return *reinterpret_cast<ushort*>(&hb);
}

__device__ __forceinline__ float bfval(ushort u) {
  unsigned int b = ((unsigned int)u) << 16;
  return __uint_as_float(b);
}

// ---------------- node 1: 512 blocks x 64 thr, plain stores only -----------
// block = (itile = blk&3, jc = blk>>2). Computes Uhat partial rows
// ws[(itile*32+row)*128 + jc] for its 32 coarse rows. No atomics, no init.
__global__ __launch_bounds__(64) void pair_kernel(
    const float* __restrict__ f,  const float* __restrict__ W1,
    const float* __restrict__ b1, const float* __restrict__ W2,
    const float* __restrict__ b2, const float* __restrict__ W3,
    float* __restrict__ ws)
{
  const int t     = threadIdx.x;
  const int blk   = blockIdx.x;
  const int half  = t >> 5;
  const int c     = t & 31;
  const int itile = blk & 3;
  const int jc    = blk >> 2;

  // ---- B fragments + column-sum (free, in the load loop) -------------------
  bf16x8s B0[4], B1[4];
  float csp0 = 0.0f, csp1 = 0.0f;
  #pragma unroll
  for (int ks = 0; ks < 4; ++ks) {
    #pragma unroll
    for (int e = 0; e < 8; ++e) {
      int k = ks * 16 + half * 8 + e;
      ushort u0 = bf16bits(-2.0f * SCL * W2[k * HH + c]);
      ushort u1 = bf16bits(-2.0f * SCL * W2[k * HH + 32 + c]);
      B0[ks][e] = (short)u0;  csp0 += bfval(u0);
      B1[ks][e] = (short)u1;  csp1 += bfval(u1);
    }
  }
  csp0 += __shfl_xor(csp0, 32);       // lanes l, l^32 hold complementary k-halves
  csp1 += __shfl_xor(csp1, 32);
  const float cst0 = fmaf(-0.5f, csp0, SCL * b2[c]);        // SCL*(b2+colsum)
  const float cst1 = fmaf(-0.5f, csp1, SCL * b2[32 + c]);

  // ---- A / C fragments: exp2 of separable layer-1 parts --------------------
  const float yr = ynode(itile * 32 + c);
  const float yj = ynode(jc);
  f32x4 Af[8], Cf[8];
  #pragma unroll
  for (int ks = 0; ks < 4; ++ks) {
    #pragma unroll
    for (int q = 0; q < 2; ++q) {
      #pragma unroll
      for (int e = 0; e < 4; ++e) {
        int m = ks * 16 + half * 8 + q * 4 + e;
        Af[ks * 2 + q][e] = __builtin_amdgcn_exp2f(SCL * yr * W1[m]);
        Cf[ks * 2 + q][e] = __builtin_amdgcn_exp2f(SCL * fmaf(yj, W1[HH + m], b1[m]));
      }
    }
  }

  // ---- ghat(jc) = sum_j w(j,jc) * f[j] * DY --------------------------------
  float g = 0.0f;
  {
    int jlo = (int)ceilf((float)(jc - 1) * INV);
    if (jlo < 0) jlo = 0;
    #pragma unroll 1
    for (int s = 0; s < 18; ++s) {
      int j = jlo + s;
      if (j > 1023) break;
      float w = 1.0f - fabsf((float)j * CJ - (float)jc);
      if (w > 0.0f) g = fmaf(w, f[j], g);
    }
  }
  const float fjv = g * DYF;
  const float wg0 = -2.0f * W3[c] * fjv;
  const float wg1 = -2.0f * W3[32 + c] * fjv;

  // ---- layer-1 r values -> bf16 -> MFMA ------------------------------------
  f32x16 acc0, acc1;
  #pragma unroll
  for (int r = 0; r < 16; ++r) { acc0[r] = cst0; acc1[r] = cst1; }

  #pragma unroll
  for (int ks = 0; ks < 4; ++ks) {
    float tt[8];
    f32x4 z0 = Af[ks * 2]     * Cf[ks * 2];       // exp2(a'+c')
    f32x4 z1 = Af[ks * 2 + 1] * Cf[ks * 2 + 1];
    #pragma unroll
    for (int e = 0; e < 4; ++e) {
      tt[e]     = __builtin_amdgcn_rcpf(z0[e] + 1.0f);
      tt[4 + e] = __builtin_amdgcn_rcpf(z1[e] + 1.0f);
    }
    union { bf16x8s s; __hip_bfloat162 h[4]; } fr;
    fr.h[0] = __float22bfloat162_rn(make_float2(tt[0], tt[1]));
    fr.h[1] = __float22bfloat162_rn(make_float2(tt[2], tt[3]));
    fr.h[2] = __float22bfloat162_rn(make_float2(tt[4], tt[5]));
    fr.h[3] = __float22bfloat162_rn(make_float2(tt[6], tt[7]));
    acc0 = __builtin_amdgcn_mfma_f32_32x32x16_bf16(fr.s, B0[ks], acc0, 0, 0, 0);
    acc1 = __builtin_amdgcn_mfma_f32_32x32x16_bf16(fr.s, B1[ks], acc1, 0, 0, 0);
  }

  // ---- epilogue tanh + W3-dot, butterfly-reduce, plain store ---------------
  #pragma unroll
  for (int r = 0; r < 16; ++r) {
    float e0 = __builtin_amdgcn_exp2f(acc0[r]);
    float r0 = __builtin_amdgcn_rcpf(e0 + 1.0f);
    float e1 = __builtin_amdgcn_exp2f(acc1[r]);
    float r1 = __builtin_amdgcn_rcpf(e1 + 1.0f);
    float v = fmaf(r0, wg0, r1 * wg1);
    v += __shfl_xor(v, 1);
    v += __shfl_xor(v, 2);
    v += __shfl_xor(v, 4);
    v += __shfl_xor(v, 8);
    v += __shfl_xor(v, 16);
    if (c == 0) {
      int row = itile * 32 + (r & 3) + 8 * (r >> 2) + 4 * half;
      ws[row * 128 + jc] = v;
    }
  }
}

// ---------------- node 2: 32 blocks x 64 thr, writes out[] once -------------
// 2 threads per fine i: hom split across the pair; p==0 lane also does the
// jc-sum + lerp of ws and the final store (overwrites poison; no memset).
__global__ __launch_bounds__(64) void out_kernel(
    const float* __restrict__ f,   const float* __restrict__ ys,
    const float* __restrict__ W3,  const float* __restrict__ b3,
    const float* __restrict__ Hw1, const float* __restrict__ Hb1,
    const float* __restrict__ Hw2, const float* __restrict__ Hb2,
    const float* __restrict__ ws,  float* __restrict__ out)
{
  const int t   = threadIdx.x;
  const int gid = blockIdx.x * 64 + t;
  const int i   = gid >> 1;
  const int p   = gid & 1;

  // G = sum f (whole wave), sw3 = sum W3
  const float4* f4 = (const float4*)f;
  float G = 0.0f;
  #pragma unroll
  for (int q = 0; q < 4; ++q) {
    float4 v = f4[t * 4 + q];
    G += v.x + v.y + v.z + v.w;
  }
  G += __shfl_xor(G, 1);  G += __shfl_xor(G, 2);  G += __shfl_xor(G, 4);
  G += __shfl_xor(G, 8);  G += __shfl_xor(G, 16); G += __shfl_xor(G, 32);
  float sw3 = W3[t];
  sw3 += __shfl_xor(sw3, 1);  sw3 += __shfl_xor(sw3, 2);  sw3 += __shfl_xor(sw3, 4);
  sw3 += __shfl_xor(sw3, 8);  sw3 += __shfl_xor(sw3, 16); sw3 += __shfl_xor(sw3, 32);

  // hom: this lane's 32 channels
  const float yi = ys[i];
  float homp = 0.0f;
  #pragma unroll
  for (int q = 0; q < 32; ++q) {
    int l = p * 32 + q;
    float e = __builtin_amdgcn_exp2f(SCL * fmaf(yi, Hw1[l], Hb1[l]));
    float th = 1.0f - 2.0f * __builtin_amdgcn_rcpf(e + 1.0f);   // tanh
    homp = fmaf(Hw2[l], th, homp);
  }
  homp += __shfl_xor(homp, 1);        // combine the pair's halves

  if (p == 0) {
    float pos = (float)i * CJ;
    int I0 = (int)pos;
    if (I0 > 126) I0 = 126;
    float tt = pos - (float)I0;
    const float4* w4 = (const float4*)ws;
    float4 s0 = {0.0f, 0.0f, 0.0f, 0.0f};
    float4 s1 = {0.0f, 0.0f, 0.0f, 0.0f};
    #pragma unroll
    for (int q = 0; q < 32; ++q) {
      float4 a = w4[I0 * 32 + q];
      float4 b = w4[(I0 + 1) * 32 + q];
      s0.x += a.x; s0.y += a.y; s0.z += a.z; s0.w += a.w;
      s1.x += b.x; s1.y += b.y; s1.z += b.z; s1.w += b.w;
    }
    float a0 = (s0.x + s0.y) + (s0.z + s0.w);
    float a1 = (s1.x + s1.y) + (s1.z + s1.w);
    out[i] = fmaf(tt, a1 - a0, a0) + homp + Hb2[0] + (b3[0] + sw3) * G * DYF;
  }
}

extern "C" void kernel_launch(void* const* d_in, const int* in_sizes, int n_in,
                              void* d_out, int out_size, void* d_ws, size_t ws_size,
                              hipStream_t stream) {
  const float* f   = (const float*)d_in[0];
  const float* ys  = (const float*)d_in[1];
  const float* W1  = (const float*)d_in[2];
  const float* b1  = (const float*)d_in[3];
  const float* W2  = (const float*)d_in[4];
  const float* b2  = (const float*)d_in[5];
  const float* W3  = (const float*)d_in[6];
  const float* b3  = (const float*)d_in[7];
  const float* Hw1 = (const float*)d_in[8];
  const float* Hb1 = (const float*)d_in[9];
  const float* Hw2 = (const float*)d_in[10];
  const float* Hb2 = (const float*)d_in[11];
  float* out = (float*)d_out;
  float* ws  = (float*)d_ws;          // 128*128 f32 partials, fully rewritten

  pair_kernel<<<512, 64, 0, stream>>>(f, W1, b1, W2, b2, W3, ws);
  out_kernel<<<32, 64, 0, stream>>>(f, ys, W3, b3, Hw1, Hb1, Hw2, Hb2, ws, out);
}

// Round 13
// 14.458 us; speedup vs baseline: 6.5886x; 1.1590x over previous
//
#include <hip/hip_runtime.h>
#include <hip/hip_bf16.h>

#define HH   64
#define DYF  0.0009765625f            // 1/1024
#define SCL  2.8853900817779268f      // 2*log2(e): tanh(x) = 1 - 2/(2^(SCL*x)+1)
#define CJ   (127.0f / 1023.0f)       // fine index -> coarse position
#define INV  (1023.0f / 127.0f)       // coarse -> fine

typedef __attribute__((ext_vector_type(4)))  float f32x4;
typedef __attribute__((ext_vector_type(16))) float f32x16;
typedef __attribute__((ext_vector_type(8)))  short bf16x8s;

// coarse node y-value: linspace(DY, 1-DY, 128)
__device__ __forceinline__ float ynode(int m) {
  return DYF + (float)m * ((1.0f - 2.0f * DYF) / 127.0f);
}

__device__ __forceinline__ ushort bf16bits(float v) {
  __hip_bfloat16 hb = __float2bfloat16(v);
  return *reinterpret_cast<ushort*>(&hb);
}

__device__ __forceinline__ float bfval(ushort u) {
  unsigned int b = ((unsigned int)u) << 16;
  return __uint_as_float(b);
}

// ---------------- single node: 127 blocks x 512 threads ---------------------
// Block I computes U(I) and U(I+1) fully (waves 0-3: I, waves 4-7: I+1; each
// wave one 32-jc tile), then writes out[i] for the 8-9 fine i's with lerp
// interval [I, I+1]. Plain stores only; block-internal sync only.
// MFMA orientation: A-rows = jc (fragment rule identical to prior rounds),
// B = W2 fragments (verbatim R12), contraction over m, cols = layer-2 l.
__global__ __launch_bounds__(512) void fused_kernel(
    const float* __restrict__ f,   const float* __restrict__ ys,
    const float* __restrict__ W1,  const float* __restrict__ b1,
    const float* __restrict__ W2,  const float* __restrict__ b2,
    const float* __restrict__ W3,  const float* __restrict__ b3,
    const float* __restrict__ Hw1, const float* __restrict__ Hb1,
    const float* __restrict__ Hw2, const float* __restrict__ Hb2,
    float* __restrict__ out)
{
  __shared__ float UPL[8];      // per-wave U partials: [0..3]=I, [4..7]=I+1
  __shared__ float homL[9];
  __shared__ float GL, SW3L;

  const int t    = threadIdx.x;
  const int wid  = t >> 6;            // wave 0..7
  const int l    = t & 63;
  const int half = l >> 5;
  const int c    = l & 31;
  const int I    = blockIdx.x;        // 0..126
  const int Iw   = I + (wid >> 2);    // this wave's coarse row (I or I+1)
  const int jt   = wid & 3;           // jc tile 0..3
  const int jc   = jt * 32 + c;       // this lane's coarse j (A-frag row)

  // owned fine-i range: i with floor(i*CJ) clamped == I
  const int i_lo = (I * 1023 + 126) / 127;
  const int i_hi = (I == 126) ? 1023 : ((I + 1) * 1023 + 126) / 127 - 1;
  const int n_i  = i_hi - i_lo + 1;   // 8 or 9

  // ---- B fragments + column-sum (R12 verbatim) -----------------------------
  bf16x8s B0[4], B1[4];
  float csp0 = 0.0f, csp1 = 0.0f;
  #pragma unroll
  for (int ks = 0; ks < 4; ++ks) {
    #pragma unroll
    for (int e = 0; e < 8; ++e) {
      int k = ks * 16 + half * 8 + e;
      ushort u0 = bf16bits(-2.0f * SCL * W2[k * HH + c]);
      ushort u1 = bf16bits(-2.0f * SCL * W2[k * HH + 32 + c]);
      B0[ks][e] = (short)u0;  csp0 += bfval(u0);
      B1[ks][e] = (short)u1;  csp1 += bfval(u1);
    }
  }
  csp0 += __shfl_xor(csp0, 32);
  csp1 += __shfl_xor(csp1, 32);
  const float cst0 = fmaf(-0.5f, csp0, SCL * b2[c]);        // SCL*(b2+colsum), col c
  const float cst1 = fmaf(-0.5f, csp1, SCL * b2[32 + c]);   // col 32+c

  // ---- A-frag ingredients: Cf (lane's jc row) x AfI (wave's coarse row) ----
  const float yj = ynode(jc);
  const float yI = ynode(Iw);
  f32x4 AfI[8], Cf[8];
  #pragma unroll
  for (int ks = 0; ks < 4; ++ks) {
    #pragma unroll
    for (int q = 0; q < 2; ++q) {
      #pragma unroll
      for (int e = 0; e < 4; ++e) {
        int m = ks * 16 + half * 8 + q * 4 + e;
        AfI[ks * 2 + q][e] = __builtin_amdgcn_exp2f(SCL * yI * W1[m]);
        Cf[ks * 2 + q][e]  = __builtin_amdgcn_exp2f(SCL * fmaf(yj, W1[HH + m], b1[m]));
      }
    }
  }

  // ---- ghat(jc) raw gather (DY folded into w3d below) ----------------------
  float gval = 0.0f;
  {
    int jlo = (int)ceilf((float)(jc - 1) * INV);
    if (jlo < 0) jlo = 0;
    #pragma unroll 1
    for (int s = 0; s < 18; ++s) {
      int j = jlo + s;
      if (j > 1023) break;
      float w = 1.0f - fabsf((float)j * CJ - (float)jc);
      if (w > 0.0f) gval = fmaf(w, f[j], gval);
    }
  }
  const float w3d0 = -2.0f * DYF * W3[c];
  const float w3d1 = -2.0f * DYF * W3[32 + c];

  // ---- layer-1 r -> bf16 -> MFMA (rows = jc, cols = l) ---------------------
  f32x16 acc0, acc1;
  #pragma unroll
  for (int r = 0; r < 16; ++r) { acc0[r] = cst0; acc1[r] = cst1; }

  #pragma unroll
  for (int ks = 0; ks < 4; ++ks) {
    float tt[8];
    f32x4 z0 = AfI[ks * 2]     * Cf[ks * 2];      // exp2(a'_I + c'_jc)
    f32x4 z1 = AfI[ks * 2 + 1] * Cf[ks * 2 + 1];
    #pragma unroll
    for (int e = 0; e < 4; ++e) {
      tt[e]     = __builtin_amdgcn_rcpf(z0[e] + 1.0f);
      tt[4 + e] = __builtin_amdgcn_rcpf(z1[e] + 1.0f);
    }
    union { bf16x8s s; __hip_bfloat162 h[4]; } fr;
    fr.h[0] = __float22bfloat162_rn(make_float2(tt[0], tt[1]));
    fr.h[1] = __float22bfloat162_rn(make_float2(tt[2], tt[3]));
    fr.h[2] = __float22bfloat162_rn(make_float2(tt[4], tt[5]));
    fr.h[3] = __float22bfloat162_rn(make_float2(tt[6], tt[7]));
    acc0 = __builtin_amdgcn_mfma_f32_32x32x16_bf16(fr.s, B0[ks], acc0, 0, 0, 0);
    acc1 = __builtin_amdgcn_mfma_f32_32x32x16_bf16(fr.s, B1[ks], acc1, 0, 0, 0);
  }

  // ---- epilogue: tanh, weight by ghat[row]*W3[col], full 64-lane reduce ----
  float s0 = 0.0f, s1 = 0.0f;
  #pragma unroll
  for (int r = 0; r < 16; ++r) {
    int row = (r & 3) + 8 * (r >> 2) + 4 * half;
    float g_r = __shfl(gval, row);               // lane `row` holds ghat(jt*32+row)
    float e0 = __builtin_amdgcn_exp2f(acc0[r]);
    float r0 = __builtin_amdgcn_rcpf(e0 + 1.0f);
    float e1 = __builtin_amdgcn_exp2f(acc1[r]);
    float r1 = __builtin_amdgcn_rcpf(e1 + 1.0f);
    s0 = fmaf(r0, g_r, s0);
    s1 = fmaf(r1, g_r, s1);
  }
  float v = fmaf(s0, w3d0, s1 * w3d1);
  v += __shfl_xor(v, 1);
  v += __shfl_xor(v, 2);
  v += __shfl_xor(v, 4);
  v += __shfl_xor(v, 8);
  v += __shfl_xor(v, 16);
  v += __shfl_xor(v, 32);
  if (l == 0) UPL[wid] = v;

  // ---- hom for wave's owned fine i (lane = channel) ------------------------
  {
    int i_loc = wid;
    if (i_loc < n_i) {
      float yi = ys[i_lo + i_loc];
      float e = __builtin_amdgcn_exp2f(SCL * fmaf(yi, Hw1[l], Hb1[l]));
      float th = 1.0f - 2.0f * __builtin_amdgcn_rcpf(e + 1.0f);   // tanh
      float h = Hw2[l] * th;
      h += __shfl_xor(h, 1);  h += __shfl_xor(h, 2);  h += __shfl_xor(h, 4);
      h += __shfl_xor(h, 8);  h += __shfl_xor(h, 16); h += __shfl_xor(h, 32);
      if (l == 0) homL[i_loc] = h;
    }
    if (n_i == 9 && wid == 0) {                  // 9th i handled by wave 0
      float yi = ys[i_lo + 8];
      float e = __builtin_amdgcn_exp2f(SCL * fmaf(yi, Hw1[l], Hb1[l]));
      float th = 1.0f - 2.0f * __builtin_amdgcn_rcpf(e + 1.0f);
      float h = Hw2[l] * th;
      h += __shfl_xor(h, 1);  h += __shfl_xor(h, 2);  h += __shfl_xor(h, 4);
      h += __shfl_xor(h, 8);  h += __shfl_xor(h, 16); h += __shfl_xor(h, 32);
      if (l == 0) homL[8] = h;
    }
  }

  // ---- G = sum f, sw3 = sum W3 (wave 1) ------------------------------------
  if (wid == 1) {
    const float4* f4 = (const float4*)f;
    float G = 0.0f;
    #pragma unroll
    for (int q = 0; q < 4; ++q) {
      float4 fv = f4[l * 4 + q];
      G += fv.x + fv.y + fv.z + fv.w;
    }
    G += __shfl_xor(G, 1);  G += __shfl_xor(G, 2);  G += __shfl_xor(G, 4);
    G += __shfl_xor(G, 8);  G += __shfl_xor(G, 16); G += __shfl_xor(G, 32);
    float sw3 = W3[l];
    sw3 += __shfl_xor(sw3, 1);  sw3 += __shfl_xor(sw3, 2);  sw3 += __shfl_xor(sw3, 4);
    sw3 += __shfl_xor(sw3, 8);  sw3 += __shfl_xor(sw3, 16); sw3 += __shfl_xor(sw3, 32);
    if (l == 0) { GL = G; SW3L = sw3; }
  }

  __syncthreads();

  // ---- final: out[i] = lerp(U(I),U(I+1)) + hom + const, plain store --------
  if (t < n_i) {
    int i = i_lo + t;
    float U0 = (UPL[0] + UPL[1]) + (UPL[2] + UPL[3]);
    float U1 = (UPL[4] + UPL[5]) + (UPL[6] + UPL[7]);
    float tt = (float)i * CJ - (float)I;
    out[i] = fmaf(tt, U1 - U0, U0) + homL[t] + Hb2[0]
             + (b3[0] + SW3L) * GL * DYF;
  }
}

extern "C" void kernel_launch(void* const* d_in, const int* in_sizes, int n_in,
                              void* d_out, int out_size, void* d_ws, size_t ws_size,
                              hipStream_t stream) {
  const float* f   = (const float*)d_in[0];
  const float* ys  = (const float*)d_in[1];
  const float* W1  = (const float*)d_in[2];
  const float* b1  = (const float*)d_in[3];
  const float* W2  = (const float*)d_in[4];
  const float* b2  = (const float*)d_in[5];
  const float* W3  = (const float*)d_in[6];
  const float* b3  = (const float*)d_in[7];
  const float* Hw1 = (const float*)d_in[8];
  const float* Hb1 = (const float*)d_in[9];
  const float* Hw2 = (const float*)d_in[10];
  const float* Hb2 = (const float*)d_in[11];
  float* out = (float*)d_out;

  fused_kernel<<<127, 512, 0, stream>>>(f, ys, W1, b1, W2, b2, W3, b3,
                                        Hw1, Hb1, Hw2, Hb2, out);
}